// Round 1
// baseline (152.691 us; speedup 1.0000x reference)
//
#include <hip/hip_runtime.h>

namespace {
constexpr int Bn = 4096;
constexpr int Ln = 2048;
constexpr float TAU = 0.85f;
constexpr float MARGIN = 0.0005f;
constexpr float RW = 0.5f;
constexpr float CW = 0.5f;

constexpr int THREADS = 256;   // 4 waves; 8 elems/thread covers L=2048
constexpr int EPT = Ln / THREADS;
static_assert(EPT == 8, "layout assumption");

// One block per row. Fused: cumsum -> softmax(q) -> JS/KL vs cut_y,
// rerank sums, BCE. Each input element is read exactly once (float4).
__global__ __launch_bounds__(THREADS) void mt_row_kernel(
    const float* __restrict__ pred,
    const float* __restrict__ rerank,
    const float* __restrict__ cut,
    const float* __restrict__ labels,
    float* __restrict__ part)
{
  const int row  = blockIdx.x;
  const int tid  = threadIdx.x;
  const int lane = tid & 63;
  const int wid  = tid >> 6;
  const size_t base = (size_t)row * Ln + (size_t)tid * EPT;

  __shared__ float wtot[4];
  __shared__ float smax[4];
  __shared__ float ssumS[4];
  __shared__ float sacc[4][4];

  // ---- labels: load + thread-local inclusive prefix ----
  float4 la = *reinterpret_cast<const float4*>(labels + base);
  float4 lb = *reinterpret_cast<const float4*>(labels + base + 4);
  float lab[8] = {la.x, la.y, la.z, la.w, lb.x, lb.y, lb.z, lb.w};
  float pref[8];
  float run = 0.f;
  #pragma unroll
  for (int j = 0; j < 8; ++j) { run += lab[j]; pref[j] = run; }
  const float own = run;

  // wave-level inclusive scan of per-thread totals (values are small ints: exact)
  float sc = own;
  #pragma unroll
  for (int off = 1; off < 64; off <<= 1) {
    float n = __shfl_up(sc, off, 64);
    if (lane >= off) sc += n;
  }
  if (lane == 63) wtot[wid] = sc;
  __syncthreads();
  float woff = 0.f;
  #pragma unroll
  for (int w = 0; w < 4; ++w) if (w < wid) woff += wtot[w];
  const float T = wtot[0] + wtot[1] + wtot[2] + wtot[3];
  const float excl = woff + sc - own;   // exclusive prefix for this thread

  // ---- z = (2c/(k+T))/TAU, row max ----
  float e[8];
  float zmax = -3.4e38f;
  const float kbase = (float)(tid * EPT);
  #pragma unroll
  for (int j = 0; j < 8; ++j) {
    float c = excl + pref[j];
    float k = kbase + (float)(j + 1);
    float z = (2.f * c / (k + T)) * (1.f / TAU);
    e[j] = z;
    zmax = fmaxf(zmax, z);
  }
  #pragma unroll
  for (int off = 32; off > 0; off >>= 1) zmax = fmaxf(zmax, __shfl_xor(zmax, off, 64));
  if (lane == 0) smax[wid] = zmax;
  __syncthreads();
  zmax = fmaxf(fmaxf(smax[0], smax[1]), fmaxf(smax[2], smax[3]));

  // ---- exp + row sum ----
  float esum = 0.f;
  #pragma unroll
  for (int j = 0; j < 8; ++j) { e[j] = __expf(e[j] - zmax); esum += e[j]; }
  #pragma unroll
  for (int off = 32; off > 0; off >>= 1) esum += __shfl_xor(esum, off, 64);
  if (lane == 0) ssumS[wid] = esum;
  __syncthreads();
  esum = ssumS[0] + ssumS[1] + ssumS[2] + ssumS[3];
  const float inv = 1.f / esum;

  // ---- symmetric KL vs cut_y ----
  float4 pa = *reinterpret_cast<const float4*>(cut + base);
  float4 pb = *reinterpret_cast<const float4*>(cut + base + 4);
  float p[8] = {pa.x, pa.y, pa.z, pa.w, pb.x, pb.y, pb.z, pb.w};
  float kl = 0.f;
  #pragma unroll
  for (int j = 0; j < 8; ++j) {
    float q  = e[j] * inv;                    // softmax output, > 0
    float lm = __logf((p[j] + q) * 0.5f);
    kl += q * (__logf(q) - lm) + p[j] * (__logf(p[j]) - lm);
  }

  // ---- rerank sums ----
  float4 sa = *reinterpret_cast<const float4*>(rerank + base);
  float4 sb = *reinterpret_cast<const float4*>(rerank + base + 4);
  float sv[8] = {sa.x, sa.y, sa.z, sa.w, sb.x, sb.y, sb.z, sb.w};
  float s_all = 0.f, s_pos = 0.f;
  #pragma unroll
  for (int j = 0; j < 8; ++j) { s_all += sv[j]; s_pos += sv[j] * lab[j]; }

  // ---- BCE (labels are exactly 0.0/1.0) ----
  float4 ya = *reinterpret_cast<const float4*>(pred + base);
  float4 yb = *reinterpret_cast<const float4*>(pred + base + 4);
  float y[8] = {ya.x, ya.y, ya.z, ya.w, yb.x, yb.y, yb.z, yb.w};
  float bce = 0.f;
  #pragma unroll
  for (int j = 0; j < 8; ++j) {
    float x = (lab[j] == 1.f) ? y[j] : (1.f - y[j]);
    bce += __logf(x);
  }

  // ---- block-reduce 4 scalars ----
  #pragma unroll
  for (int off = 32; off > 0; off >>= 1) {
    kl    += __shfl_xor(kl,    off, 64);
    s_all += __shfl_xor(s_all, off, 64);
    s_pos += __shfl_xor(s_pos, off, 64);
    bce   += __shfl_xor(bce,   off, 64);
  }
  if (lane == 0) { sacc[wid][0] = kl; sacc[wid][1] = s_all; sacc[wid][2] = s_pos; sacc[wid][3] = bce; }
  __syncthreads();
  if (tid == 0) {
    part[0 * Bn + row] = sacc[0][0] + sacc[1][0] + sacc[2][0] + sacc[3][0];
    part[1 * Bn + row] = sacc[0][1] + sacc[1][1] + sacc[2][1] + sacc[3][1];
    part[2 * Bn + row] = sacc[0][2] + sacc[1][2] + sacc[2][2] + sacc[3][2];
    part[3 * Bn + row] = sacc[0][3] + sacc[1][3] + sacc[2][3] + sacc[3][3];
    part[4 * Bn + row] = T;
  }
}

// Single block: reduce 4096 per-row partials in double, emit scalar.
__global__ __launch_bounds__(256) void mt_final_kernel(
    const float* __restrict__ part, float* __restrict__ out)
{
  const int tid  = threadIdx.x;
  const int lane = tid & 63;
  const int wid  = tid >> 6;
  double kl = 0, sv = 0, sp = 0, bc = 0, tt = 0;
  for (int r = tid; r < Bn; r += 256) {
    kl += (double)part[0 * Bn + r];
    sv += (double)part[1 * Bn + r];
    sp += (double)part[2 * Bn + r];
    bc += (double)part[3 * Bn + r];
    tt += (double)part[4 * Bn + r];
  }
  #pragma unroll
  for (int off = 32; off > 0; off >>= 1) {
    kl += __shfl_xor(kl, off, 64);
    sv += __shfl_xor(sv, off, 64);
    sp += __shfl_xor(sp, off, 64);
    bc += __shfl_xor(bc, off, 64);
    tt += __shfl_xor(tt, off, 64);
  }
  __shared__ double sh[4][5];
  if (lane == 0) { sh[wid][0] = kl; sh[wid][1] = sv; sh[wid][2] = sp; sh[wid][3] = bc; sh[wid][4] = tt; }
  __syncthreads();
  if (tid == 0) {
    kl = sh[0][0] + sh[1][0] + sh[2][0] + sh[3][0];
    sv = sh[0][1] + sh[1][1] + sh[2][1] + sh[3][1];
    sp = sh[0][2] + sh[1][2] + sh[2][2] + sh[3][2];
    bc = sh[0][3] + sh[1][3] + sh[2][3] + sh[3][3];
    tt = sh[0][4] + sh[1][4] + sh[2][4] + sh[3][4];
    const double total = (double)Bn * (double)Ln;
    const double posc = tt, negc = total - tt;
    double rer = (sv - sp) / negc - sp / posc + (double)MARGIN;  // neg_mean - pos_mean + margin
    if (rer < 0.0) rer = 0.0;
    rer *= (double)RW;
    const double cutl = 0.5 * kl / (double)Bn;
    const double bcel = -(bc / total) * (double)CW;
    out[0] = (float)(cutl + rer + bcel);
  }
}
} // namespace

extern "C" void kernel_launch(void* const* d_in, const int* in_sizes, int n_in,
                              void* d_out, int out_size, void* d_ws, size_t ws_size,
                              hipStream_t stream) {
  const float* pred   = (const float*)d_in[0];  // pred_y   (B,L,1)
  const float* rerank = (const float*)d_in[1];  // rerank_y (B,L,1)
  const float* cut    = (const float*)d_in[2];  // cut_y    (B,L,1)
  const float* labels = (const float*)d_in[3];  // labels   (B,L)
  float* part = (float*)d_ws;                   // 5 * Bn floats = 80 KB
  mt_row_kernel<<<Bn, THREADS, 0, stream>>>(pred, rerank, cut, labels, part);
  mt_final_kernel<<<1, 256, 0, stream>>>(part, (float*)d_out);
}